// Round 1
// 187.151 us; speedup vs baseline: 1.0101x; 1.0101x over previous
//
#include <hip/hip_runtime.h>
#include <math.h>

#define BROWS 4096
#define NCOLS 8192
#define LLEN  256
#define EPSV  1e-8f
#define RPB   4        // rows per block = 1 row per wave, 4 waves

// compare-exchange: x keeps max iff xmax
#define CMPEX(x, y, xmax) {                         \
    unsigned _mx = (x) > (y) ? (x) : (y);           \
    unsigned _mn = (x) > (y) ? (y) : (x);           \
    (x) = (xmax) ? _mx : _mn;                       \
    (y) = (xmax) ? _mn : _mx; }

__global__ __launch_bounds__(256) void listmle_kernel(
    const float* __restrict__ logits,
    const int*   __restrict__ ids,
    const float* __restrict__ weights,
    float*       __restrict__ partial)
{
    // per-row (g, w) pairs for the post-sort gather; wave-local, no barriers
    __shared__ float2 s_gw[RPB][LLEN];

    const int tid  = threadIdx.x;
    const int lane = tid & 63;
    const int wv   = tid >> 6;
    const int row  = blockIdx.x * RPB + wv;

    // ---- coalesced vector loads: 16B/lane (G13)
    const int4   id4 = reinterpret_cast<const int4*>(ids + (size_t)row * LLEN)[lane];
    const float4 w4  = reinterpret_cast<const float4*>(weights + (size_t)row * LLEN)[lane];
    const float* lrow = logits + (size_t)row * NCOLS;

    // ---- 4 independent random gathers per lane (4x MLP vs old kernel).
    // First use is after the whole sort -> latency hidden under shuffles.
    float g0 = lrow[id4.x];
    float g1 = lrow[id4.y];
    float g2 = lrow[id4.z];
    float g3 = lrow[id4.w];

    // ---- sort keys: top-24 bits of w (w in [0,1) => bits order-monotone),
    // low 8 bits = reversed original position (stable tie-break).
    const int e0 = lane << 2;           // this lane's first element index
    unsigned k0 = (__float_as_uint(w4.x) & 0xFFFFFF00u) | (unsigned)(255 - (e0 + 0));
    unsigned k1 = (__float_as_uint(w4.y) & 0xFFFFFF00u) | (unsigned)(255 - (e0 + 1));
    unsigned k2 = (__float_as_uint(w4.z) & 0xFFFFFF00u) | (unsigned)(255 - (e0 + 2));
    unsigned k3 = (__float_as_uint(w4.w) & 0xFFFFFF00u) | (unsigned)(255 - (e0 + 3));

    // ---- bitonic sort of 256 keys, 4 elems/lane, single wave, ZERO barriers.
    // Same network as the verified 256-thread version: element e keeps max
    // iff ((e&k)==0) == ((e&j)==0); final k=256 stage => descending order.
    // j>=4: partner elem e^j lives in lane^(j>>2), same register slot.
    //       e&k and e&j depend only on lane bits (k>=8, j>=4) -> one bool.
    // j==2: in-lane pairs (0,2),(1,3).  j==1: in-lane pairs (0,1),(2,3).
    #pragma unroll
    for (int k = 2; k <= 256; k <<= 1) {
        #pragma unroll
        for (int j = k >> 1; j > 0; j >>= 1) {
            if (j >= 4) {
                const int  lj = j >> 2;
                const bool km = (((e0 & k) == 0) == ((e0 & j) == 0));
                unsigned p0 = __shfl_xor(k0, lj);
                unsigned p1 = __shfl_xor(k1, lj);
                unsigned p2 = __shfl_xor(k2, lj);
                unsigned p3 = __shfl_xor(k3, lj);
                { unsigned mx = k0 > p0 ? k0 : p0, mn = k0 > p0 ? p0 : k0; k0 = km ? mx : mn; }
                { unsigned mx = k1 > p1 ? k1 : p1, mn = k1 > p1 ? p1 : k1; k1 = km ? mx : mn; }
                { unsigned mx = k2 > p2 ? k2 : p2, mn = k2 > p2 ? p2 : k2; k2 = km ? mx : mn; }
                { unsigned mx = k3 > p3 ? k3 : p3, mn = k3 > p3 ? p3 : k3; k3 = km ? mx : mn; }
            } else if (j == 2) {
                const bool km = ((e0 & k) == 0);     // i-bits don't reach k (k>=4)
                CMPEX(k0, k2, km);
                CMPEX(k1, k3, km);
            } else {                                  // j == 1
                bool km01, km23;
                if (k == 2) { km01 = true; km23 = false; }
                else        { km01 = km23 = ((e0 & k) == 0); }
                CMPEX(k0, k1, km01);
                CMPEX(k2, k3, km23);
            }
        }
    }

    // ---- publish (g, w) by ORIGINAL element index; two ds_write_b128
    float2* sw = s_gw[wv];
    reinterpret_cast<float4*>(sw)[lane * 2 + 0] = make_float4(g0, w4.x, g1, w4.y);
    reinterpret_cast<float4*>(sw)[lane * 2 + 1] = make_float4(g2, w4.z, g3, w4.w);
    __builtin_amdgcn_wave_barrier();   // keep write->read ordering in-schedule

    // sorted slot s = 4*lane+i holds key; recover original position
    const int p0i = 255 - (int)(k0 & 0xFFu);
    const int p1i = 255 - (int)(k1 & 0xFFu);
    const int p2i = 255 - (int)(k2 & 0xFFu);
    const int p3i = 255 - (int)(k3 & 0xFFu);
    const float2 gw0 = sw[p0i];
    const float2 gw1 = sw[p1i];
    const float2 gw2 = sw[p2i];
    const float2 gw3 = sw[p3i];

    // ---- suffix sums of exp (plain fp32: logits ~ N(0,1), no overflow risk;
    // 256-term fp32 sum rel-err ~1.5e-5, far under tolerance)
    const float x0 = __expf(gw0.x);
    const float x1 = __expf(gw1.x);
    const float x2 = __expf(gw2.x);
    const float x3 = __expf(gw3.x);

    const float lt = x0 + x1 + x2 + x3;          // lane total
    float S = lt;                                 // inclusive suffix scan over lanes
    #pragma unroll
    for (int off = 1; off < 64; off <<= 1) {
        float sp = __shfl_down(S, off);
        if (lane + off < 64) S += sp;
    }
    const float tail = S - lt;                    // sum over lanes > this one
    const float s3 = x3 + tail;
    const float s2 = x2 + s3;
    const float s1 = x1 + s2;
    const float s0 = x0 + s1;

    // ---- weighted terms + weight sum, wave reduce (no barriers)
    float t  = gw0.y * (__logf(s0) - gw0.x)
             + gw1.y * (__logf(s1) - gw1.x)
             + gw2.y * (__logf(s2) - gw2.x)
             + gw3.y * (__logf(s3) - gw3.x);
    float ws = gw0.y + gw1.y + gw2.y + gw3.y;
    #pragma unroll
    for (int off = 32; off > 0; off >>= 1) {
        t  += __shfl_down(t, off);
        ws += __shfl_down(ws, off);
    }
    if (lane == 0) partial[row] = t / fmaxf(ws, EPSV);
}

__global__ __launch_bounds__(256) void reduce_kernel(
    const float* __restrict__ partial, float* __restrict__ out)
{
    __shared__ float s_red[4];
    const int tid  = threadIdx.x;
    const int lane = tid & 63;
    const int wv   = tid >> 6;

    float v = 0.0f;
    #pragma unroll
    for (int i = 0; i < BROWS / 256; ++i)
        v += partial[i * 256 + tid];

    #pragma unroll
    for (int o = 32; o > 0; o >>= 1) v += __shfl_down(v, o);
    if (lane == 0) s_red[wv] = v;
    __syncthreads();
    if (tid == 0)
        out[0] = (s_red[0] + s_red[1] + s_red[2] + s_red[3]) * (1.0f / (float)BROWS);
}

extern "C" void kernel_launch(void* const* d_in, const int* in_sizes, int n_in,
                              void* d_out, int out_size, void* d_ws, size_t ws_size,
                              hipStream_t stream) {
    const float* logits  = (const float*)d_in[0];
    const int*   ids     = (const int*)d_in[1];
    const float* weights = (const float*)d_in[2];
    float* out     = (float*)d_out;
    float* partial = (float*)d_ws;   // 4096 floats of scratch

    listmle_kernel<<<dim3(BROWS / RPB), dim3(256), 0, stream>>>(logits, ids, weights, partial);
    reduce_kernel<<<dim3(1), dim3(256), 0, stream>>>(partial, out);
}